// Round 8
// baseline (193.647 us; speedup 1.0000x reference)
//
#include <hip/hip_runtime.h>
#include <stdint.h>

typedef unsigned int u32;
typedef int v4i  __attribute__((ext_vector_type(4)));
typedef int v16i __attribute__((ext_vector_type(16)));

#define K_MSG   1024
#define N_CODE  2048
#define NB      32768
#define BM 128
#define BN 128
#define BK 64
#define BKP 80              // padded LDS stride (avoid 16-way bank conflict at 64)

// ---------------- pack b -> i8: [NB][1024] int32 -> [NB][1024] i8 -----------
__global__ void pack_bi8(const int* __restrict__ b, u32* __restrict__ bi8) {
    const int nthr = gridDim.x * blockDim.x;
    int idx = blockIdx.x * blockDim.x + threadIdx.x;
    const int ndw = NB * K_MSG / 4;                 // output dwords
    for (; idx < ndw; idx += nthr) {
        int4 v = *(const int4*)(b + (size_t)idx * 4);
        bi8[idx] = (u32)(v.x & 1) | ((u32)(v.y & 1) << 8) |
                   ((u32)(v.z & 1) << 16) | ((u32)(v.w & 1) << 24);
    }
}

// ------------- pack G -> i8 transposed: GT8[j][k] = G[k][j] & 1 -------------
// idx = kq*2048 + j (consecutive threads -> consecutive j: coalesced G reads)
__global__ void pack_gT8(const int* __restrict__ G, u32* __restrict__ gt8) {
    int idx = blockIdx.x * blockDim.x + threadIdx.x;   // 524288 total
    const int j  = idx & (N_CODE - 1);
    const int kq = idx >> 11;                          // 0..255
    u32 p = 0;
#pragma unroll
    for (int i = 0; i < 4; ++i) {
        int v = G[(size_t)(kq * 4 + i) * N_CODE + j];
        p |= (u32)(v & 1) << (8 * i);
    }
    gt8[(size_t)j * (K_MSG / 4) + kq] = p;             // GT8[j][k]: byte k of row j
}

// ---------------- i8 MFMA GEMM: out = (bi8 @ G) & 1 ------------------------
// 256 thr = 4 waves (2x2 wave grid, 64x64 per wave, 2x2 frags of 32x32).
// A_lds[row][k] row-major, B_lds[col][k] col-major (from GT8), both BKP=80.
// Frag maps (32x32x32_i8): A: row=lane&31, k=(lane>>5)*16+e (b128 read).
//                          B: col=lane&31, k=(lane>>5)*16+e.
//            C/D (verified): col=lane&31, row=(r&3)+8*(r>>2)+4*(lane>>5).
__global__ __launch_bounds__(256) void gemm_i8(const char* __restrict__ bi8,
                                               const char* __restrict__ gt8,
                                               int* __restrict__ out) {
    __shared__ __align__(16) char As[2][BM][BKP];
    __shared__ __align__(16) char Bs[2][BN][BKP];

    const int t    = threadIdx.x;
    const int m0   = blockIdx.y * BM;
    const int n0   = blockIdx.x * BN;
    const int srow = t & 127;          // staging row (A) / col (B)
    const int kh   = t >> 7;           // 0..1: which 32B half of the 64B k-slice
    const int w    = t >> 6, lane = t & 63, hi = lane >> 5, lr = lane & 31;
    const int wm   = w >> 1, wn = w & 1;

    v16i acc[2][2] = {};

    const char* aseg = bi8 + (size_t)(m0 + srow) * K_MSG + kh * 32;
    const char* bseg = gt8 + (size_t)(n0 + srow) * K_MSG + kh * 32;

    // stage step 0
    {
        uint4 a0 = *(const uint4*)(aseg);
        uint4 a1 = *(const uint4*)(aseg + 16);
        uint4 b0 = *(const uint4*)(bseg);
        uint4 b1 = *(const uint4*)(bseg + 16);
        *(uint4*)&As[0][srow][kh * 32]      = a0;
        *(uint4*)&As[0][srow][kh * 32 + 16] = a1;
        *(uint4*)&Bs[0][srow][kh * 32]      = b0;
        *(uint4*)&Bs[0][srow][kh * 32 + 16] = b1;
    }
    __syncthreads();

    const int NSTEP = K_MSG / BK;      // 16
#pragma unroll 1
    for (int s = 0; s < NSTEP; ++s) {
        const int cur = s & 1, nxt = cur ^ 1;
        uint4 na0, na1, nb0, nb1;
        if (s < NSTEP - 1) {           // issue next-step global loads early
            const char* ap = aseg + (size_t)(s + 1) * BK;
            const char* bp = bseg + (size_t)(s + 1) * BK;
            na0 = *(const uint4*)(ap);      na1 = *(const uint4*)(ap + 16);
            nb0 = *(const uint4*)(bp);      nb1 = *(const uint4*)(bp + 16);
        }
#pragma unroll
        for (int kc = 0; kc < 2; ++kc) {
            v4i af0 = *(const v4i*)&As[cur][wm * 64 + lr]      [kc * 32 + hi * 16];
            v4i af1 = *(const v4i*)&As[cur][wm * 64 + 32 + lr] [kc * 32 + hi * 16];
            v4i bf0 = *(const v4i*)&Bs[cur][wn * 64 + lr]      [kc * 32 + hi * 16];
            v4i bf1 = *(const v4i*)&Bs[cur][wn * 64 + 32 + lr] [kc * 32 + hi * 16];
            acc[0][0] = __builtin_amdgcn_mfma_i32_32x32x32_i8(af0, bf0, acc[0][0], 0, 0, 0);
            acc[0][1] = __builtin_amdgcn_mfma_i32_32x32x32_i8(af0, bf1, acc[0][1], 0, 0, 0);
            acc[1][0] = __builtin_amdgcn_mfma_i32_32x32x32_i8(af1, bf0, acc[1][0], 0, 0, 0);
            acc[1][1] = __builtin_amdgcn_mfma_i32_32x32x32_i8(af1, bf1, acc[1][1], 0, 0, 0);
        }
        if (s < NSTEP - 1) {
            *(uint4*)&As[nxt][srow][kh * 32]      = na0;
            *(uint4*)&As[nxt][srow][kh * 32 + 16] = na1;
            *(uint4*)&Bs[nxt][srow][kh * 32]      = nb0;
            *(uint4*)&Bs[nxt][srow][kh * 32 + 16] = nb1;
        }
        __syncthreads();
    }

    // epilogue: parity = acc & 1
#pragma unroll
    for (int fm = 0; fm < 2; ++fm) {
#pragma unroll
        for (int fn = 0; fn < 2; ++fn) {
            const int rbase = m0 + wm * 64 + fm * 32 + 4 * hi;
            const int cbase = n0 + wn * 64 + fn * 32 + lr;
#pragma unroll
            for (int r = 0; r < 16; ++r) {
                const int row = rbase + (r & 3) + 8 * (r >> 2);
                out[(size_t)row * N_CODE + cbase] = acc[fm][fn][r] & 1;
            }
        }
    }
}

// ---------------- fallback (only if ws too small) ---------------------------
__global__ void encode_naive(const int* __restrict__ b, const int* __restrict__ G,
                             int* __restrict__ out) {
    size_t idx = (size_t)blockIdx.x * blockDim.x + threadIdx.x;
    size_t total = (size_t)NB * N_CODE;
    if (idx >= total) return;
    int i = (int)(idx / N_CODE);
    int j = (int)(idx % N_CODE);
    int acc = 0;
    for (int k = 0; k < K_MSG; ++k)
        acc ^= b[(size_t)i * K_MSG + k] & G[(size_t)k * N_CODE + j];
    out[idx] = acc & 1;
}

extern "C" void kernel_launch(void* const* d_in, const int* in_sizes, int n_in,
                              void* d_out, int out_size, void* d_ws, size_t ws_size,
                              hipStream_t stream) {
    const int* b = (const int*)d_in[0];
    const int* G = (const int*)d_in[1];
    int* out = (int*)d_out;

    const size_t bi8_bytes = (size_t)NB * K_MSG;          // 32 MiB
    const size_t gt8_bytes = (size_t)N_CODE * K_MSG;      // 2 MiB

    if (ws_size < bi8_bytes + gt8_bytes) {
        size_t total = (size_t)NB * N_CODE;
        encode_naive<<<(unsigned)((total + 255) / 256), 256, 0, stream>>>(b, G, out);
        return;
    }

    char* bi8 = (char*)d_ws;
    char* gt8 = (char*)d_ws + bi8_bytes;

    pack_bi8<<<2048, 256, 0, stream>>>(b, (u32*)bi8);
    pack_gT8<<<2048, 256, 0, stream>>>(G, (u32*)gt8);

    dim3 grid(N_CODE / BN, NB / BM);   // 16 x 256 = 4096 blocks
    gemm_i8<<<grid, 256, 0, stream>>>(bi8, gt8, out);
}